// Round 12
// baseline (670.543 us; speedup 1.0000x reference)
//
#include <hip/hip_runtime.h>

// VQ-VAE vector-quantize, fused: distances + argmin + gather + loss.
// x: [65536, 256] fp32, dict: [256, 1024] fp32.
// out: q_ste [65536*256] fp32, then loss scalar at out[65536*256].
//
// NUMERICS (bit-exact vs np reference, verified absmax 0.0 R2-R16 — DO NOT CHANGE):
//  - row norm ||f||^2: np pairwise tree (two 128-halves, 8 accumulators
//    r8[e&7], unfused squares, fixed combine tree, halfv0 + h1) — R7-verified
//    single-thread body, now one lane per row.
//  - enorm ||e||^2: sequential d ascending, unfused square then plain add
//  - dot chain per (row,code): fmaf, d = 0..255 strictly ascending per ct,
//    acc zeroed per ct — lane-sequential, textually R12's chain.
//  - dist = fl( fl(A + B) - 2*s ); lane-local argmin strict < with codes
//    ascending (first-index on ties); cross-wave combine via the associative
//    rule (v<bv)||(v==bv && i<bi) — deterministic, order-independent.
//  - STE out = fl(x + fl(q - x)); loss on pure q, (1+BETA)/(N*D) scale
//
// PERF (R16 -> R17): ledger closed: 17.3k cyc/CU-step = 8.2k FMA + 2.9k other
// VALU + 6.2k stall, and the stall is STRUCTURAL (per-step vmcnt(0)+barrier
// lockstep; every reg-level fix spills against the 128-float acc). R17 changes
// the decomposition instead: wave owns a UNIFORM 64-code slice (e via scalar/
// uniform loads — off LDS and off VALU), lane owns one full row (f = private
// dwordx4 from x, L1-resident window). NO LDS staging, NO main-loop barriers:
// waves fully independent -> 4 waves/SIMD TLP covers e/f latency (m114).
// acc[64]+misc ~= 95 VGPR < 128 cap. FMA floor unchanged (218 us).

#define NROWS 65536
#define DDIM  256
#define KC    1024
#define BM    64             // rows per block = lanes per wave
#define NCT   4              // 4 code-tiles of 256
#define BETA_SCALE (1.25f / 16777216.0f)   // (1+BETA)/(N*D)

// Pre-kernel: codebook column norms (np order: rounded square then plain add,
// sequential d ascending) + transposed codebook (for epilogue gather) + loss
// zero-init. 16 blocks x 64 threads.
__global__ __launch_bounds__(64) void vq_prep(const float* __restrict__ dict,
                                              float* __restrict__ enorm,
                                              float* __restrict__ dictT,
                                              float* __restrict__ loss) {
#pragma clang fp contract(off)
    int k = blockIdx.x * 64 + threadIdx.x;
    if (k == 0) *loss = 0.f;   // runs before vq_main (stream order)
    float s = 0.f;
    #pragma unroll 8
    for (int d = 0; d < DDIM; ++d) {
        float v = dict[(size_t)d * KC + k];
        float sq = v * v;          // rounded square (np temp array)
        s = s + sq;                // plain add, NOT fma (chain stays sequential)
        dictT[(size_t)k * DDIM + d] = v;
    }
    enorm[k] = s;
}

__global__ __launch_bounds__(256, 4) void vq_main(const float* __restrict__ x,
                                                  const float* __restrict__ dict,
                                                  const float* __restrict__ enorm,
                                                  const float* __restrict__ dictT,
                                                  float* __restrict__ out,
                                                  float* __restrict__ loss) {
    __shared__ float cmbv[4][BM];        // per-wave argmin candidates
    __shared__ int   cmbi[4][BM];
    __shared__ int   idx_s[BM];

    const int tid = threadIdx.x;
    const int l   = tid & 63;            // lane = row within block
    const int w   = tid >> 6;            // wave = code-slice owner
    // wave-uniform copy for scalar addressing of the e-operands
    const int wu  = __builtin_amdgcn_readfirstlane(w);
    const int rowbase = blockIdx.x * BM;
    const int row = rowbase + l;
    const float* __restrict__ xr = x + (size_t)row * DDIM;

    // ---- Per-lane row norm: R7-verified np two-half chain (full row).
    float Arow;
    {
#pragma clang fp contract(off)
        float r8[8] = {0.f, 0.f, 0.f, 0.f, 0.f, 0.f, 0.f, 0.f};
        float halfv0 = 0.f;
        #pragma unroll 8
        for (int c = 0; c < 64; ++c) {   // d = 4c..4c+3 ; (4c+k)&7 = (c&1)*4+k
            float4 v = *(const float4*)&xr[c * 4];
            int b = (c & 1) * 4;
            float s0 = v.x * v.x; r8[b + 0] = r8[b + 0] + s0;
            float s1 = v.y * v.y; r8[b + 1] = r8[b + 1] + s1;
            float s2 = v.z * v.z; r8[b + 2] = r8[b + 2] + s2;
            float s3 = v.w * v.w; r8[b + 3] = r8[b + 3] + s3;
            if (c == 31) {               // half boundary at elem 128
                halfv0 = ((r8[0] + r8[1]) + (r8[2] + r8[3]))
                       + ((r8[4] + r8[5]) + (r8[6] + r8[7]));
                #pragma unroll
                for (int j = 0; j < 8; ++j) r8[j] = 0.f;
            }
        }
        float h1 = ((r8[0] + r8[1]) + (r8[2] + r8[3]))
                 + ((r8[4] + r8[5]) + (r8[6] + r8[7]));
        Arow = halfv0 + h1;              // fl(half0 + half1) — verified chain
    }

    float minv = 3.4e38f;
    int   mini = 0;

    // ---- Main: 4 ct passes, NO barriers, NO LDS. Per lane: its row (VGPR
    // dwordx4, L1-hot) x the wave's 64 codes (uniform loads -> scalar path).
    float acc[64];
    for (int ct = 0; ct < NCT; ++ct) {
        const int cb = ct * 256 + wu * 64;           // wave-uniform code base
        #pragma unroll
        for (int c = 0; c < 64; ++c) acc[c] = 0.f;

        float4 xv = *(const float4*)&xr[0];
        #pragma unroll 2
        for (int dq = 0; dq < 64; ++dq) {            // d = 4*dq + dl, ascending
            const int nq = (dq < 63) ? dq + 1 : 63;
            float4 nxt = *(const float4*)&xr[nq * 4];   // prefetch next d-quad
            #pragma unroll
            for (int dl = 0; dl < 4; ++dl) {
                const float fv = (dl == 0) ? xv.x : (dl == 1) ? xv.y
                               : (dl == 2) ? xv.z : xv.w;
                const float* __restrict__ eb =
                    dict + (size_t)(dq * 4 + dl) * KC + cb;  // uniform address
                #pragma unroll
                for (int c = 0; c < 64; ++c)
                    acc[c] = fmaf(fv, eb[c], acc[c]);
            }
            xv = nxt;
        }

        // Finalize this ct: dist = fl( fl(A + B) - 2*s ), strict < keeps
        // FIRST min (codes ascend within lane across c and across ct).
        const float* __restrict__ enb = enorm + cb;  // uniform address
        #pragma unroll
        for (int c = 0; c < 64; ++c) {
            float t1 = Arow + enb[c];
            float dist = t1 - 2.0f * acc[c];
            if (dist < minv) { minv = dist; mini = cb + c; }
        }
    }

    // ---- Cross-wave argmin combine (4 candidates per row). The rule is
    // associative & commutative -> deterministic first-index result.
    cmbv[w][l] = minv;
    cmbi[w][l] = mini;
    __syncthreads();
    if (w == 0) {
        float bv = cmbv[0][l]; int bi = cmbi[0][l];
        #pragma unroll
        for (int ww = 1; ww < 4; ++ww) {
            float v = cmbv[ww][l]; int i = cmbi[ww][l];
            if (v < bv || (v == bv && i < bi)) { bv = v; bi = i; }
        }
        idx_s[l] = bi;
    }
    __syncthreads();

    // Epilogue: gather codebook row (dictT L2-resident), re-read x (L1/L3-hot),
    // emulate STE out = fl(x + fl(q-x)), loss on pure q (before STE).
    // 256 threads x 1 col over 64 rows; per-element chains unchanged
    // (lsum regrouping harness-tolerated per R8/R14). Nontemporal stores.
    float lsum = 0.f;
    {
#pragma clang fp contract(off)
        #pragma unroll 2
        for (int i = 0; i < BM; ++i) {
            int k = idx_s[i];
            float qv = dictT[(size_t)k * DDIM + tid];
            float xv = x[(size_t)(rowbase + i) * DDIM + tid];
            float diff = qv - xv;                                 // fl(q - x)
            __builtin_nontemporal_store(xv + diff,
                &out[(size_t)(rowbase + i) * DDIM + tid]);        // fl(x + fl(q-x))
            float d = xv - qv;
            float dsq = d * d;
            lsum = lsum + dsq;
        }
    }
    #pragma unroll
    for (int off = 32; off > 0; off >>= 1)
        lsum += __shfl_down(lsum, off, 64);
    if ((tid & 63) == 0)
        atomicAdd(loss, lsum * BETA_SCALE);

}

extern "C" void kernel_launch(void* const* d_in, const int* in_sizes, int n_in,
                              void* d_out, int out_size, void* d_ws, size_t ws_size,
                              hipStream_t stream) {
    (void)in_sizes; (void)n_in; (void)out_size; (void)ws_size;
    const float* x    = (const float*)d_in[0];
    const float* dict = (const float*)d_in[1];
    float* out   = (float*)d_out;
    float* enorm = (float*)d_ws;                 // 1024 floats
    float* dictT = enorm + KC;                   // 1024*256 floats (1 MB)
    float* loss  = out + (size_t)NROWS * DDIM;   // scalar slot after q

    vq_prep<<<KC / 64, 64, 0, stream>>>(dict, enorm, dictT, loss);
    vq_main<<<NROWS / BM, 256, 0, stream>>>(x, dict, enorm, dictT, out, loss);
}

// Round 13
// 559.922 us; speedup vs baseline: 1.1976x; 1.1976x over previous
//
#include <hip/hip_runtime.h>

// VQ-VAE vector-quantize, fused: distances + argmin + gather + loss.
// x: [65536, 256] fp32, dict: [256, 1024] fp32.
// out: q_ste [65536*256] fp32, then loss scalar at out[65536*256].
//
// NUMERICS (bit-exact vs np reference, verified absmax 0.0 R2-R17 — DO NOT CHANGE):
//  - row norm ||f||^2: np pairwise tree (two INDEPENDENT 128-halves, each an
//    8-accumulator r8[e&7] chain, unfused squares, fixed combine tree,
//    result = half0_tree + half1_tree)
//  - enorm ||e||^2: sequential d ascending, unfused square then plain add
//  - dot chain per (row,code): fmaf, d strictly ascending per ct (c0 outer,
//    ddl inner — R16-verified nest), acc zeroed per ct
//  - dist = fl( fl(A + B) - 2*s ), argmin first-index on exact ties
//  - STE out = fl(x + fl(q - x)); loss on pure q, (1+BETA)/(N*D) scale
//
// PERF (R17 -> R18): R17 (wave-uniform codes) pushed acc into AGPRs (VGPR=48,
// accvgpr traffic tripled VALU work). Constraints from 12 rounds: keep the
// R12 compute core; kill the per-step vmcnt(0) drain; no reg prefetch (spills);
// DMA sources must stay line-coalesced. R18 = T3/T4 counted-vmcnt pipeline:
//  - ALL staging via global_load_lds (0 regs, 0 ds_writes), depth-2 prefetch
//    over 3 rotating buffers (pointers rotate in regs, no runtime indexing).
//  - Raw s_barrier + `s_waitcnt vmcnt(6)`: step s+2's 6 loads stay in flight
//    ACROSS the barrier, landing during step s+1's compute (m201 pattern).
//  - x granule = (row, d-quad): slot sp=row*4+c0s, c0 = c0s ^ ((row>>3)&3).
//    XOR permutes granules WITHIN each row's 64B line -> coalescing preserved
//    (R16's mistake was cross-row scatter); read side `c0 ^ (ty&3)` -> 4
//    ty-groups in 4 distinct bank-quads, conflict-free b128.

#define NROWS 65536
#define DDIM  256
#define KC    1024
#define BM    128            // rows per block
#define BC    256            // codes per ct tile
#define DC    16             // d-chunk per pipeline step
#define NDC   16             // DDIM/DC
#define NCT   4              // KC/BC
#define NSTEP 64             // NCT*NDC

typedef float v4 __attribute__((ext_vector_type(4)));

#define GLOAD_LDS16(gp, lp) __builtin_amdgcn_global_load_lds( \
    (const __attribute__((address_space(1))) void*)(gp),      \
    (__attribute__((address_space(3))) void*)(lp), 16, 0, 0)

// x chunk [128 rows][16 d] via DMA: 512 granules of 16B. Slot sp = row*4+c0s
// (lane-linear dest); global granule c0 = c0s ^ ((row>>3)&3) — a permutation
// WITHIN the row's 64B line (4 lanes per row cover one 64B segment). 2 instrs.
#define STAGE_FX_DMA(dstbuf, dc_) do {                                          \
    _Pragma("unroll")                                                           \
    for (int i_ = 0; i_ < 2; ++i_) {                                            \
        int sp_ = i_ * 256 + tid;                                               \
        int row_ = sp_ >> 2;                                                    \
        int c0_  = (sp_ & 3) ^ ((row_ >> 3) & 3);                               \
        GLOAD_LDS16(&x[(size_t)(rowbase + row_) * DDIM + (dc_) * DC + c0_ * 4], \
                    (dstbuf) + sp_ * 4);                                        \
    }                                                                           \
} while (0)

// dict tile [16 d][256 codes] via DMA: lds dest = uniform + lane*16. 4 instrs.
#define STAGE_DICT(pbuf, ct_, dc_) do {                                         \
    _Pragma("unroll")                                                           \
    for (int i_ = 0; i_ < 4; ++i_) {                                            \
        int flat_ = i_ * 256 + tid;                                             \
        int dd_ = flat_ >> 6;            /* wave-uniform */                     \
        int l4_ = (flat_ & 63) * 4;      /* lane*4 floats = lane*16 B */        \
        GLOAD_LDS16(&dict[(size_t)((dc_) * DC + dd_) * KC + (ct_) * BC + l4_],  \
                    (pbuf) + dd_ * BC + l4_);                                   \
    }                                                                           \
} while (0)

// Pre-kernel: codebook column norms (np order: rounded square then plain add,
// sequential d ascending) + transposed codebook + loss zero-init.
__global__ __launch_bounds__(64) void vq_prep(const float* __restrict__ dict,
                                              float* __restrict__ enorm,
                                              float* __restrict__ dictT,
                                              float* __restrict__ loss) {
#pragma clang fp contract(off)
    int k = blockIdx.x * 64 + threadIdx.x;
    if (k == 0) *loss = 0.f;   // runs before vq_main (stream order)
    float s = 0.f;
    #pragma unroll 8
    for (int d = 0; d < DDIM; ++d) {
        float v = dict[(size_t)d * KC + k];
        float sq = v * v;          // rounded square (np temp array)
        s = s + sq;                // plain add, NOT fma (chain stays sequential)
        dictT[(size_t)k * DDIM + d] = v;
    }
    enorm[k] = s;
}

__global__ __launch_bounds__(256, 2) void vq_main(const float* __restrict__ x,
                                                  const float* __restrict__ dict,
                                                  const float* __restrict__ enorm,
                                                  const float* __restrict__ dictT,
                                                  float* __restrict__ out,
                                                  float* __restrict__ loss) {
    __shared__ float fX3[3][512 * 4];    // 8 KB each  (x: 512 granules)
    __shared__ float dT3[3][DC * BC];    // 16 KB each -> 72 KB staging
    __shared__ float rnormS[BM];         // dedicated (no aliasing: DMA races)
    __shared__ int   idx_s[BM];          // dedicated -> total ~73 KB, 2 blk/CU

    const int tid = threadIdx.x;
    const int tx  = tid & 15;            // 16 code-groups x 16 codes = 256
    const int ty  = tid >> 4;            // 16 row-groups  x  8 rows  = 128
    const int rowbase = blockIdx.x * BM;

    // ---- Prologue: stage steps 0 and 1 (DMA overlaps the rnorm reads).
    STAGE_DICT(&dT3[0][0], 0, 0);
    STAGE_FX_DMA(&fX3[0][0], 0);
    STAGE_DICT(&dT3[1][0], 0, 1);
    STAGE_FX_DMA(&fX3[1][0], 1);

    // Block-local row norms: verified np two-half chain, 2 threads/row.
    {
#pragma clang fp contract(off)
        const int row  = tid >> 1;
        const int half = tid & 1;
        const float* xr = x + (size_t)(rowbase + row) * DDIM + half * 128;
        float r8[8] = {0.f, 0.f, 0.f, 0.f, 0.f, 0.f, 0.f, 0.f};
        #pragma unroll 8
        for (int c = 0; c < 32; ++c) {   // local e = 4c..4c+3 ; e&7 == (c&1)*4+k
            float4 v = *(const float4*)&xr[c * 4];
            int b = (c & 1) * 4;
            float s0 = v.x * v.x; r8[b + 0] = r8[b + 0] + s0;
            float s1 = v.y * v.y; r8[b + 1] = r8[b + 1] + s1;
            float s2 = v.z * v.z; r8[b + 2] = r8[b + 2] + s2;
            float s3 = v.w * v.w; r8[b + 3] = r8[b + 3] + s3;
        }
        float h = ((r8[0] + r8[1]) + (r8[2] + r8[3]))
                + ((r8[4] + r8[5]) + (r8[6] + r8[7]));
        float ho = __shfl_down(h, 1, 64);    // odd lane's half-1 tree
        if (half == 0) rnormS[row] = h + ho; // fl(half0 + half1) — verified chain
    }

    __syncthreads();                     // full drain once: s0+s1 staged, rnormS live

    // Row norms (broadcast reads: 16 lanes share ty). row = 8*ty+r.
    float Arow[8];
    #pragma unroll
    for (int r = 0; r < 8; ++r) Arow[r] = rnormS[ty * 8 + r];

    float minv[8];
    int   mini[8];
    #pragma unroll
    for (int r = 0; r < 8; ++r) { minv[r] = 3.4e38f; mini[r] = 0; }

    // Rotating buffer pointers (register-held; no runtime-indexed arrays).
    float* xcur = &fX3[0][0]; float* xn1 = &fX3[1][0]; float* xn2 = &fX3[2][0];
    float* dcur = &dT3[0][0]; float* dn1 = &dT3[1][0]; float* dn2 = &dT3[2][0];

    const int fsw = (ty & 3) << 2;       // f-read XOR (floats)

    float acc[8][16];
    // ---- Main: 64 steps. Depth-2 DMA; counted vmcnt; raw barriers.
    #pragma unroll 1
    for (int s = 0; s < NSTEP; ++s) {
        if (s < NSTEP - 2) {
            const int ns = s + 2;
            STAGE_DICT(dn2, ns >> 4, ns & 15);   // 4 loads, 0 regs
            STAGE_FX_DMA(xn2, ns & 15);          // 2 loads, 0 regs
        }
        if ((s & 15) == 0) {
            #pragma unroll
            for (int r = 0; r < 8; ++r)
                #pragma unroll
                for (int j = 0; j < 16; ++j) acc[r][j] = 0.f;
        }
        // d = c0*4 + ddl consumed strictly ascending (frozen chain order).
        #pragma unroll 1                 // region = 4 dd (R12/R16-sized)
        for (int c0 = 0; c0 < 4; ++c0) {
            v4 fq[8];
            #pragma unroll
            for (int r = 0; r < 8; ++r)
                fq[r] = *(const v4*)&xcur[(8 * ty + r) * 16 + ((c0 << 2) ^ fsw)];
            #pragma unroll
            for (int ddl = 0; ddl < 4; ++ddl) {
                const int dd = c0 * 4 + ddl;
                const v4 e0 = *(const v4*)&dcur[dd * BC + tx * 4];
                const v4 e1 = *(const v4*)&dcur[dd * BC + 64 + tx * 4];
                const v4 e2 = *(const v4*)&dcur[dd * BC + 128 + tx * 4];
                const v4 e3 = *(const v4*)&dcur[dd * BC + 192 + tx * 4];
                const float ec[16] = {e0[0], e0[1], e0[2], e0[3],
                                      e1[0], e1[1], e1[2], e1[3],
                                      e2[0], e2[1], e2[2], e2[3],
                                      e3[0], e3[1], e3[2], e3[3]};
                #pragma unroll
                for (int r = 0; r < 8; ++r) {
                    const float frv = fq[r][ddl];
                    #pragma unroll
                    for (int j = 0; j < 16; ++j)
                        acc[r][j] = fmaf(frv, ec[j], acc[r][j]);
                }
            }
        }
        if ((s & 15) == 15) {
            // dist = fl( fl(A + B) - 2*s ) — np rounding chain. Codes ascend
            // with (ct, j) for fixed tx -> strict < keeps FIRST min index.
            const int cbase = (s >> 4) * BC;
            float en[16];
            #pragma unroll
            for (int j = 0; j < 16; ++j)
                en[j] = enorm[cbase + (j >> 2) * 64 + tx * 4 + (j & 3)];
            #pragma unroll
            for (int r = 0; r < 8; ++r)
                #pragma unroll
                for (int j = 0; j < 16; ++j) {
                    int code = cbase + (j >> 2) * 64 + tx * 4 + (j & 3);
                    float t1 = Arow[r] + en[j];
                    float dist = t1 - 2.0f * acc[r][j];
                    if (dist < minv[r]) { minv[r] = dist; mini[r] = code; }
                }
        }
        // End of step: wait only for step-(s+1)'s staging (issued last step,
        // oldest); this step's 6 loads stay IN FLIGHT across the barrier.
        if (s < NSTEP - 2) {
            asm volatile("s_waitcnt vmcnt(6)" ::: "memory");
        } else {
            asm volatile("s_waitcnt vmcnt(0)" ::: "memory");
        }
        __builtin_amdgcn_sched_barrier(0);
        __builtin_amdgcn_s_barrier();
        // rotate buffers (registers only)
        { float* t = xcur; xcur = xn1; xn1 = xn2; xn2 = t; }
        { float* t = dcur; dcur = dn1; dn1 = dn2; dn2 = t; }
    }

    // Cross-lane argmin over the 16 tx lanes (xor<16 stays in-wave; lane =
    // (ty&3)*16 + tx). Tie -> smaller index (first occurrence).
    #pragma unroll
    for (int m = 1; m < 16; m <<= 1)
        #pragma unroll
        for (int r = 0; r < 8; ++r) {
            float ov = __shfl_xor(minv[r], m, 64);
            int   oi = __shfl_xor(mini[r], m, 64);
            if (ov < minv[r] || (ov == minv[r] && oi < mini[r])) {
                minv[r] = ov; mini[r] = oi;
            }
        }

    if (tx == 0) {
        #pragma unroll
        for (int r = 0; r < 8; ++r) idx_s[ty * 8 + r] = mini[r];
    }
    __syncthreads();

    // Epilogue: gather codebook row (dictT L2-resident), re-read x (L3-hot),
    // emulate STE out = fl(x + fl(q-x)), loss on pure q (before STE).
    // unroll 2 = load ILP; lsum chain order preserved. Nontemporal stores.
    float lsum = 0.f;
    {
#pragma clang fp contract(off)
        #pragma unroll 2
        for (int i = 0; i < BM; ++i) {
            int k = idx_s[i];
            float qv = dictT[(size_t)k * DDIM + tid];
            float xv = x[(size_t)(rowbase + i) * DDIM + tid];
            float diff = qv - xv;                                 // fl(q - x)
            __builtin_nontemporal_store(xv + diff,
                &out[(size_t)(rowbase + i) * DDIM + tid]);        // fl(x + fl(q-x))
            float d = xv - qv;
            float dsq = d * d;
            lsum = lsum + dsq;
        }
    }
    #pragma unroll
    for (int off = 32; off > 0; off >>= 1)
        lsum += __shfl_down(lsum, off, 64);
    if ((tid & 63) == 0)
        atomicAdd(loss, lsum * (1.25f / 16777216.0f));  // (1+BETA)/(N*D)
}

extern "C" void kernel_launch(void* const* d_in, const int* in_sizes, int n_in,
                              void* d_out, int out_size, void* d_ws, size_t ws_size,
                              hipStream_t stream) {
    (void)in_sizes; (void)n_in; (void)out_size; (void)ws_size;
    const float* x    = (const float*)d_in[0];
    const float* dict = (const float*)d_in[1];
    float* out   = (float*)d_out;
    float* enorm = (float*)d_ws;                 // 1024 floats
    float* dictT = enorm + KC;                   // 1024*256 floats (1 MB)
    float* loss  = out + (size_t)NROWS * DDIM;   // scalar slot after q

    vq_prep<<<KC / 64, 64, 0, stream>>>(dict, enorm, dictT, loss);
    vq_main<<<NROWS / BM, 256, 0, stream>>>(x, dict, enorm, dictT, out, loss);
}